// Round 3
// baseline (288.855 us; speedup 1.0000x reference)
//
#include <hip/hip_runtime.h>
#include <hip/hip_bf16.h>
#include <cstdint>
#include <cstddef>

// ---------------------------------------------------------------------------
// Self-attention, B=4 S=2048 D=1024. Inputs FLOAT32, output FLOAT32.
//   Q = x@Wq^T+bq ; K = x@Wk^T+bk ; V = x@Wv^T+bv
//   S = Q@K^T ; P = softmax(S)*(1/32) ; O = P@V
// FP16 pipeline (calibrated: absmax 4.88e-4 vs threshold 1.758e-3).
// Round-15: FIX — rounds 13/14 never compiled: the workspace comment
//   "//  2 MB  \" ended in a backslash, splicing the Wkh declaration into
//   the comment (line continuation). Removed. No functional change vs r14.
// Design (round-13): counted-vmcnt deep pipeline (T3+T4) + setprio (T5).
//   8 waves (2Mx4N, 64x64/wave), 128x256 tile, BK=64, THREE LDS buffers
//   (144 KB), distance-2 prefetch: iter t stages tile t+2, waits
//   s_waitcnt vmcnt(12) (tile t's 6 loads drained, 12 in flight), raw
//   s_barrier (no compiler vmcnt(0) drain), 2x16-MFMA phases in setprio(1).
//   vmcnt hits 0 only on the last K-tile.
//   qkv fused into ONE GEMM over N=3072 (Wqh|Wkh|Wvh contiguous in ws).
//   Grids exact multiples of 256 @ 1 block/CU: qkv 768, scores 512, pv 256.
//   XCD-aware decodes keep per-XCD L2 working set <= ~4 MB.
//   Keeps: XOR LDS swizzle (conflicts=0), global_load_lds w16, f16x4 Vt
//   stores, 2-row softmax.
// Workspace (peak 150,994,944 B):
//   Qp [8192][1024] f16 @ 0     (16 MB)
//   Kp [8192][1024] f16 @ 16M   (16 MB)
//   Vt [4][1024][2048]  @ 32M   (16 MB)  V^T per batch, f16
//   Sc [4][2048][2048]  @ 48M   (64 MB)  f32 scores
//   P  [4][2048][2048]  @ 112M  (32 MB)  f16 probs
//   xh [8192][1024] f16 @ 48M   (16 MB)  aliases Sc (dead after qkv)
//   Wh 3x[1024][1024]   @ 64M   ( 6 MB)  aliases Sc; Wq|Wk|Wv contiguous
// ---------------------------------------------------------------------------

typedef __attribute__((ext_vector_type(8))) _Float16 f16x8;
typedef __attribute__((ext_vector_type(4))) _Float16 f16x4;
typedef __attribute__((ext_vector_type(4))) float f32x4;

#define BM 128
#define BN 256
#define BK 64
#define A_TILE (BM * BK)  // 8192 halves = 16 KB
#define B_TILE (BN * BK)  // 16384 halves = 32 KB

#define NBATCH 4
#define SEQ 2048
#define DIM 1024
#define MTOT (NBATCH * SEQ)  // 8192

__device__ __forceinline__ void async_ld16(const void* g, void* l) {
  __builtin_amdgcn_global_load_lds((__attribute__((address_space(1))) void*)(g),
                                   (__attribute__((address_space(3))) void*)(l),
                                   16, 0, 0);
}

// Stage one 128x64 A-tile (2 rounds) + 256x64 B-tile (4 rounds) at k0 into
// (As,Bs). 512 threads: rb=t>>3 covers 64 rows/round, source col XOR-swizzled
// (t&7)^(rb&7); LDS dest is linear wave slot (global_load_lds = uniform base
// + lane*16B). 6 vmcnt-counted loads per thread.
__device__ __forceinline__ void stage_tile(const _Float16* __restrict__ Ap, int lda,
                                           const _Float16* __restrict__ Bp, int ldb,
                                           int k0, _Float16* As, _Float16* Bs,
                                           int w) {
#pragma unroll
  for (int i = 0; i < 2; ++i)
    async_ld16(Ap + (size_t)(i * 64) * lda + k0, As + i * 4096 + (w << 9));
#pragma unroll
  for (int i = 0; i < 4; ++i)
    async_ld16(Bp + (size_t)(i * 64) * ldb + k0, Bs + i * 4096 + (w << 9));
}

// C[m0..+127][n0..+255] += A[m,k]*B[n,k]  (row-major, B^T GEMM), f16 in,
// f32 acc. 8 waves as 2x4, each 64x64 via 4x4 of 16x16x32 f16 MFMA.
// Distance-2 counted-vmcnt pipeline over 3 LDS buffers (see header).
__device__ __forceinline__ void gemm8(const _Float16* __restrict__ A, int lda,
                                      const _Float16* __restrict__ B, int ldb,
                                      int K, int m0, int n0,
                                      _Float16* sA, _Float16* sB,
                                      f32x4 (&acc)[4][4]) {
  const int t = threadIdx.x;
  const int w = t >> 6;
  const int lrow = t & 15;
  const int quad = (t >> 4) & 3;
  const int wm = (w >> 2) << 6;   // 0/64
  const int wn = (w & 3) << 6;    // 0/64/128/192
  const int rb = t >> 3;          // staging row 0..63
  const int co = (((t & 7) ^ (rb & 7)) << 3);  // XOR-swizzled source col
  const _Float16* Ap = A + (size_t)(m0 + rb) * lda + co;
  const _Float16* Bp = B + (size_t)(n0 + rb) * ldb + co;
  const int sw = lrow & 7;        // row-phase for read-side swizzle

  _Float16 *A0 = sA, *A1 = sA + A_TILE, *A2 = sA + 2 * A_TILE;
  _Float16 *B0 = sB, *B1 = sB + B_TILE, *B2 = sB + 2 * B_TILE;

  const int nt = K >> 6;  // >= 3 for all call sites (16 or 32)
  stage_tile(Ap, lda, Bp, ldb, 0, A0, B0, w);
  stage_tile(Ap, lda, Bp, ldb, BK, A1, B1, w);

  for (int tt = 0; tt < nt; ++tt) {
    // Prefetch tile tt+2 into the buffer freed at iter tt-1's end barrier.
    if (tt + 2 < nt) {
      stage_tile(Ap, lda, Bp, ldb, (tt + 2) * BK, A2, B2, w);
      asm volatile("s_waitcnt vmcnt(12)" ::: "memory");  // tile tt landed
    } else if (tt + 1 < nt) {
      asm volatile("s_waitcnt vmcnt(6)" ::: "memory");   // tail: tile tt landed
    } else {
      asm volatile("s_waitcnt vmcnt(0)" ::: "memory");   // last tile
    }
    asm volatile("" ::: "memory");       // IR fence: nothing crosses barrier
    __builtin_amdgcn_s_barrier();        // all waves' tile-tt loads visible
    asm volatile("" ::: "memory");
    __builtin_amdgcn_sched_barrier(0);   // no ds_read hoists above barrier

#pragma unroll
    for (int kk = 0; kk < BK; kk += 32) {
      const int slot = ((kk >> 3) + quad) ^ sw;  // swizzled 8-elt slot
      f16x8 af[4], bf[4];
#pragma unroll
      for (int mi = 0; mi < 4; ++mi)
        af[mi] = *(const f16x8*)(A0 + (wm + mi * 16 + lrow) * BK + (slot << 3));
#pragma unroll
      for (int ni = 0; ni < 4; ++ni)
        bf[ni] = *(const f16x8*)(B0 + (wn + ni * 16 + lrow) * BK + (slot << 3));
      __builtin_amdgcn_s_setprio(1);
#pragma unroll
      for (int mi = 0; mi < 4; ++mi)
#pragma unroll
        for (int ni = 0; ni < 4; ++ni)
          acc[mi][ni] = __builtin_amdgcn_mfma_f32_16x16x32_f16(af[mi], bf[ni],
                                                               acc[mi][ni], 0, 0, 0);
      __builtin_amdgcn_s_setprio(0);
    }

    asm volatile("" ::: "memory");       // IR fence: reads stay above barrier
    __builtin_amdgcn_s_barrier();        // readers done before restaging buf
    asm volatile("" ::: "memory");
    __builtin_amdgcn_sched_barrier(0);   // next stage can't hoist above
    _Float16* ta = A0; A0 = A1; A1 = A2; A2 = ta;
    _Float16* tb = B0; B0 = B1; B1 = B2; B2 = tb;
  }
}

// ---------------------------------------------------------------------------
// Kernel 0: fused f32 -> f16 cast for x, Wq, Wk, Wv (W's land contiguous).
__global__ __launch_bounds__(256) void split_all_kernel(
    const float* __restrict__ x, const float* __restrict__ Wq,
    const float* __restrict__ Wk, const float* __restrict__ Wv,
    _Float16* __restrict__ xh, _Float16* __restrict__ Wqh,
    _Float16* __restrict__ Wkh, _Float16* __restrict__ Wvh) {
  int r = blockIdx.x;
  const float* src;
  _Float16* dst;
  if (r < MTOT)            { src = x;  dst = xh;  }
  else if (r < MTOT + DIM) { src = Wq; dst = Wqh; r -= MTOT; }
  else if (r < MTOT + 2 * DIM) { src = Wk; dst = Wkh; r -= MTOT + DIM; }
  else                     { src = Wv; dst = Wvh; r -= MTOT + 2 * DIM; }
  const int t = threadIdx.x;
  const float4 v = ((const float4*)(src + (size_t)r * DIM))[t];
  f16x4 hi = {(_Float16)v.x, (_Float16)v.y, (_Float16)v.z, (_Float16)v.w};
  ((f16x4*)(dst + (size_t)r * DIM))[t] = hi;
}

// ---------------------------------------------------------------------------
// Kernel 1: fused QKV projection, one GEMM: [8192,1024] x [3072,1024]^T.
// Grid 768 = 64 m-tiles x 12 n-tiles, 3 exact passes @ 1 block/CU.
// Decode: xcd=l&7 owns m-slab xcd*8..+8 (A 2 MB L2-resident); n streams.
__global__ __launch_bounds__(512, 1) void qkv_kernel(
    const _Float16* __restrict__ xh, const _Float16* __restrict__ Wcat,
    const float* __restrict__ bq, const float* __restrict__ bk,
    const float* __restrict__ bv,
    _Float16* __restrict__ Qp, _Float16* __restrict__ Kp,
    _Float16* __restrict__ Vt) {
  __shared__ alignas(16) _Float16 sA[3 * A_TILE];
  __shared__ alignas(16) _Float16 sB[3 * B_TILE];
  f32x4 acc[4][4] = {};
  const int l = blockIdx.x;
  const int xcd = l & 7;
  const int i = l >> 3;                     // 0..95
  const int m0 = (xcd * 8 + (i & 7)) * BM;  // 64 m-tiles
  const int n0 = (i >> 3) * BN;             // 12 n-tiles over 3072
  gemm8(xh, DIM, Wcat, DIM, DIM, m0, n0, sA, sB, acc);

  const int t = threadIdx.x, w = t >> 6, lrow = t & 15, quad = (t >> 4) & 3;
  const int wm = (w >> 2) << 6, wn = (w & 3) << 6;
  const int z = n0 >> 10;           // 0=Q 1=K 2=V
  const int ncol = (n0 & 1023) + wn;
  if (z == 2) {
    // Vt[b][col][s]: 4 consecutive s per (mi,ni) -> vectorized f16x4 store.
    const int b = m0 >> 11;
    const int s_base = (m0 & (SEQ - 1)) + wm + quad * 4;
#pragma unroll
    for (int ni = 0; ni < 4; ++ni) {
      const int col = ncol + ni * 16 + lrow;
      const float bb = bv[col];
      _Float16* vrow = Vt + (size_t)((b << 10) + col) * SEQ;
#pragma unroll
      for (int mi = 0; mi < 4; ++mi) {
        f16x4 v4 = {(_Float16)(acc[mi][ni][0] + bb),
                    (_Float16)(acc[mi][ni][1] + bb),
                    (_Float16)(acc[mi][ni][2] + bb),
                    (_Float16)(acc[mi][ni][3] + bb)};
        *(f16x4*)(vrow + s_base + mi * 16) = v4;
      }
    }
  } else {
    const float* bias = (z == 0) ? bq : bk;
    _Float16* base = (z == 0) ? Qp : Kp;
#pragma unroll
    for (int ni = 0; ni < 4; ++ni) {
      const int col = ncol + ni * 16 + lrow;
      const float bb = bias[col];
#pragma unroll
      for (int mi = 0; mi < 4; ++mi) {
#pragma unroll
        for (int r = 0; r < 4; ++r) {
          const int row = m0 + wm + mi * 16 + quad * 4 + r;
          base[(size_t)row * DIM + col] = (_Float16)(acc[mi][ni][r] + bb);
        }
      }
    }
  }
}

// ---------------------------------------------------------------------------
// Kernel 2: scores[b] = Q[b] @ K[b]^T (K=1024), f32 out. Grid 512 = 4 b x
// (16 m x 8 n), 2 exact passes. XCD 2D decode: xm=xcd&1 (8 m-tiles),
// xn=xcd>>1 (2 n-tiles) -> per-XCD working set ~3 MB/batch.
__global__ __launch_bounds__(512, 1) void scores_kernel(
    const _Float16* __restrict__ Qp, const _Float16* __restrict__ Kp,
    float* __restrict__ Sc) {
  __shared__ alignas(16) _Float16 sA[3 * A_TILE];
  __shared__ alignas(16) _Float16 sB[3 * B_TILE];
  f32x4 acc[4][4] = {};
  const int l = blockIdx.x;
  const int b = l >> 7;
  const int r = l & 127;
  const int xcd = r & 7;
  const int i = r >> 3;                              // 0..15
  const int m0 = ((xcd & 1) * 8 + (i & 7)) * BM;     // 16 m-tiles
  const int n0 = (((xcd >> 1) << 1) + (i >> 3)) * BN;  // 8 n-tiles
  gemm8(Qp + (size_t)b * SEQ * DIM, DIM,
        Kp + (size_t)b * SEQ * DIM, DIM, DIM, m0, n0, sA, sB, acc);
  float* out = Sc + (size_t)b * SEQ * SEQ;
  const int t = threadIdx.x, w = t >> 6, lrow = t & 15, quad = (t >> 4) & 3;
  const int wm = (w >> 2) << 6, wn = (w & 3) << 6;
#pragma unroll
  for (int ni = 0; ni < 4; ++ni) {
    const int col = n0 + wn + ni * 16 + lrow;
#pragma unroll
    for (int mi = 0; mi < 4; ++mi) {
#pragma unroll
      for (int r2 = 0; r2 < 4; ++r2) {
        const int row = m0 + wm + mi * 16 + quad * 4 + r2;
        out[(size_t)row * SEQ + col] = acc[mi][ni][r2];
      }
    }
  }
}

// ---------------------------------------------------------------------------
// Kernel 3: row softmax, 2 rows per block (ILP), P = softmax(S)*(1/32), f16.
__global__ __launch_bounds__(256) void softmax_kernel(const float* __restrict__ Sc,
                                                      _Float16* __restrict__ P) {
  const int r0 = blockIdx.x * 2;  // rows r0, r0+1
  const float* rowA = Sc + (size_t)r0 * SEQ;
  const float* rowB = rowA + SEQ;
  _Float16* prowA = P + (size_t)r0 * SEQ;
  _Float16* prowB = prowA + SEQ;
  const int t = threadIdx.x;
  const int w = t >> 6;

  const float4 a0 = ((const float4*)rowA)[t];
  const float4 a1 = ((const float4*)rowA)[t + 256];
  const float4 b0 = ((const float4*)rowB)[t];
  const float4 b1 = ((const float4*)rowB)[t + 256];

  float mA = fmaxf(fmaxf(fmaxf(a0.x, a0.y), fmaxf(a0.z, a0.w)),
                   fmaxf(fmaxf(a1.x, a1.y), fmaxf(a1.z, a1.w)));
  float mB = fmaxf(fmaxf(fmaxf(b0.x, b0.y), fmaxf(b0.z, b0.w)),
                   fmaxf(fmaxf(b1.x, b1.y), fmaxf(b1.z, b1.w)));
#pragma unroll
  for (int o = 32; o; o >>= 1) {
    mA = fmaxf(mA, __shfl_down(mA, o));
    mB = fmaxf(mB, __shfl_down(mB, o));
  }
  __shared__ float red[16];
  if ((t & 63) == 0) { red[w] = mA; red[w + 4] = mB; }
  __syncthreads();
  mA = fmaxf(fmaxf(red[0], red[1]), fmaxf(red[2], red[3]));
  mB = fmaxf(fmaxf(red[4], red[5]), fmaxf(red[6], red[7]));

  float eA[8], eB[8];
  eA[0] = __expf(a0.x - mA); eA[1] = __expf(a0.y - mA);
  eA[2] = __expf(a0.z - mA); eA[3] = __expf(a0.w - mA);
  eA[4] = __expf(a1.x - mA); eA[5] = __expf(a1.y - mA);
  eA[6] = __expf(a1.z - mA); eA[7] = __expf(a1.w - mA);
  eB[0] = __expf(b0.x - mB); eB[1] = __expf(b0.y - mB);
  eB[2] = __expf(b0.z - mB); eB[3] = __expf(b0.w - mB);
  eB[4] = __expf(b1.x - mB); eB[5] = __expf(b1.y - mB);
  eB[6] = __expf(b1.z - mB); eB[7] = __expf(b1.w - mB);
  float sA = ((eA[0] + eA[1]) + (eA[2] + eA[3])) + ((eA[4] + eA[5]) + (eA[6] + eA[7]));
  float sB = ((eB[0] + eB[1]) + (eB[2] + eB[3])) + ((eB[4] + eB[5]) + (eB[6] + eB[7]));
#pragma unroll
  for (int o = 32; o; o >>= 1) {
    sA += __shfl_down(sA, o);
    sB += __shfl_down(sB, o);
  }
  if ((t & 63) == 0) { red[8 + w] = sA; red[12 + w] = sB; }
  __syncthreads();
  sA = (red[8] + red[9]) + (red[10] + red[11]);
  sB = (red[12] + red[13]) + (red[14] + red[15]);

  const float scA = 0.03125f / sA;  // post-softmax 1/sqrt(Dk)=1/32 folded in
  const float scB = 0.03125f / sB;
  f16x4 oA0 = {(_Float16)(eA[0] * scA), (_Float16)(eA[1] * scA),
               (_Float16)(eA[2] * scA), (_Float16)(eA[3] * scA)};
  f16x4 oA1 = {(_Float16)(eA[4] * scA), (_Float16)(eA[5] * scA),
               (_Float16)(eA[6] * scA), (_Float16)(eA[7] * scA)};
  f16x4 oB0 = {(_Float16)(eB[0] * scB), (_Float16)(eB[1] * scB),
               (_Float16)(eB[2] * scB), (_Float16)(eB[3] * scB)};
  f16x4 oB1 = {(_Float16)(eB[4] * scB), (_Float16)(eB[5] * scB),
               (_Float16)(eB[6] * scB), (_Float16)(eB[7] * scB)};
  ((f16x4*)prowA)[t] = oA0;
  ((f16x4*)prowA)[t + 256] = oA1;
  ((f16x4*)prowB)[t] = oB0;
  ((f16x4*)prowB)[t + 256] = oB1;
}

// ---------------------------------------------------------------------------
// Kernel 4: O[b] = P[b] @ V[b]  (Vt [v][s] -> B^T GEMM, K=2048), f32 out.
// Grid 256 = 4 b x (16 m x 4 n), 1 exact pass. XCD 2D decode: xm=xcd&3
// (4 m-tiles), xn=xcd>>2 (2 n-tiles) -> per-XCD ~4 MB L2 working set.
__global__ __launch_bounds__(512, 1) void pv_kernel(
    const _Float16* __restrict__ P, const _Float16* __restrict__ Vt,
    float* __restrict__ out) {
  __shared__ alignas(16) _Float16 sA[3 * A_TILE];
  __shared__ alignas(16) _Float16 sB[3 * B_TILE];
  f32x4 acc[4][4] = {};
  const int l = blockIdx.x;
  const int b = l >> 6;
  const int r = l & 63;
  const int xcd = r & 7;
  const int i = r >> 3;                                // 0..7
  const int m0 = ((xcd & 3) * 4 + (i & 3)) * BM;       // 16 m-tiles
  const int n0 = (((xcd >> 2) << 1) + (i >> 2)) * BN;  // 4 n-tiles
  gemm8(P + (size_t)b * SEQ * SEQ, SEQ,
        Vt + (size_t)b * DIM * SEQ, SEQ, SEQ, m0, n0, sA, sB, acc);
  float* ob = out + (size_t)b * SEQ * DIM;
  const int t = threadIdx.x, w = t >> 6, lrow = t & 15, quad = (t >> 4) & 3;
  const int wm = (w >> 2) << 6, wn = (w & 3) << 6;
#pragma unroll
  for (int ni = 0; ni < 4; ++ni) {
    const int col = n0 + wn + ni * 16 + lrow;
#pragma unroll
    for (int mi = 0; mi < 4; ++mi) {
#pragma unroll
      for (int r2 = 0; r2 < 4; ++r2) {
        const int row = m0 + wm + mi * 16 + quad * 4 + r2;
        ob[(size_t)row * DIM + col] = acc[mi][ni][r2];
      }
    }
  }
}

// ---------------------------------------------------------------------------
extern "C" void kernel_launch(void* const* d_in, const int* in_sizes, int n_in,
                              void* d_out, int out_size, void* d_ws, size_t ws_size,
                              hipStream_t stream) {
  const float* x  = (const float*)d_in[0];
  const float* Wq = (const float*)d_in[1];
  const float* bq = (const float*)d_in[2];
  const float* Wk = (const float*)d_in[3];
  const float* bk = (const float*)d_in[4];
  const float* Wv = (const float*)d_in[5];
  const float* bv = (const float*)d_in[6];
  float* out = (float*)d_out;  // reference output dtype is float32

  char* ws = (char*)d_ws;
  _Float16* Qp  = (_Float16*)(ws);                 // 16 MB [8192][1024]
  _Float16* Kp  = (_Float16*)(ws + 16777216);      // 16 MB
  _Float16* Vt  = (_Float16*)(ws + 33554432);      // 16 MB [4][1024][2048]
  float*    Sc  = (float*)(ws + 50331648);         // 64 MB [4][2048][2048] f32
  _Float16* P   = (_Float16*)(ws + 117440512);     // 32 MB [4][2048][2048] f16
  // xh + W hi planes alias the Sc region (dead once scores_kernel runs).
  // Wqh/Wkh/Wvh are contiguous: together they form Wcat [3072][1024].
  _Float16* xh  = (_Float16*)(ws + 50331648);      // 16 MB [8192][1024]
  _Float16* Wqh = (_Float16*)(ws + 67108864);      //  2 MB (Wcat rows 0..1023)
  _Float16* Wkh = (_Float16*)(ws + 69206016);      //  2 MB (Wcat rows 1024..2047)
  _Float16* Wvh = (_Float16*)(ws + 71303168);      //  2 MB (Wcat rows 2048..3071)
  // peak 150,994,944 B

  split_all_kernel<<<dim3(MTOT + 3 * DIM), dim3(256), 0, stream>>>(
      x, Wq, Wk, Wv, xh, Wqh, Wkh, Wvh);
  qkv_kernel<<<dim3(768), dim3(512), 0, stream>>>(
      xh, Wqh, bq, bk, bv, Qp, Kp, Vt);
  scores_kernel<<<dim3(512), dim3(512), 0, stream>>>(Qp, Kp, Sc);
  softmax_kernel<<<dim3(MTOT / 2), dim3(256), 0, stream>>>(Sc, P);
  pv_kernel<<<dim3(256), dim3(512), 0, stream>>>(P, Vt, out);
}

// Round 4
// 236.497 us; speedup vs baseline: 1.2214x; 1.2214x over previous
//
#include <hip/hip_runtime.h>
#include <hip/hip_bf16.h>
#include <cstdint>
#include <cstddef>

// ---------------------------------------------------------------------------
// Self-attention, B=4 S=2048 D=1024. Inputs FLOAT32, output FLOAT32.
//   Q = x@Wq^T+bq ; K = x@Wk^T+bk ; V = x@Wv^T+bv
//   S = Q@K^T ; P = softmax(S)*(1/32) ; O = P@V
// FP16 pipeline (calibrated: absmax 4.88e-4 vs threshold 1.758e-3).
// Round-16: REVERT to round-12 architecture (verified 247.3 us; the r13-15
//   counted-vmcnt 512-thr core measured 615 TF vs 910 — coarse phase-split
//   without fine interleave + occupancy loss, matching m196's regression
//   data; m97-style 2-barrier core restored) + ONE safe delta:
//   Sc stored as f16 (was f32). Halves scores' write traffic and softmax's
//   fetch (64 MB saved round-trip). |S|<~60 so f16 quant err <=0.016 abs ->
//   P rel err ~1.6% -> O err ~few e-4; threshold headroom 3.6x.
// Keeps: XOR LDS swizzle (conflicts=0), global_load_lds w16, K=1024
//   hi-plane GEMMs, f16x4 Vt stores, 2-row softmax, 8x8 super-tile
//   XCD-aware block decode on qkv/scores/pv.
// Workspace (peak 150,994,944 B):
//   Qp [8192][1024] f16 @ 0     (16 MB)
//   Kp [8192][1024] f16 @ 16M   (16 MB)
//   Vt [4][1024][2048]  @ 32M   (16 MB)  V^T per batch, f16
//   Sc [4][2048][2048]  @ 48M   (32 MB)  f16 scores (was f32)
//   P  [4][2048][2048]  @ 112M  (32 MB)  f16 probs
//   xh [8192][1024] f16 @ 48M   (16 MB)  aliases Sc (dead after qkv)
//   Wh 3x[1024][1024]   @ 64M   ( 6 MB)  aliases Sc tail (dead after qkv)
// ---------------------------------------------------------------------------

typedef __attribute__((ext_vector_type(8))) _Float16 f16x8;
typedef __attribute__((ext_vector_type(4))) _Float16 f16x4;
typedef __attribute__((ext_vector_type(4))) float f32x4;

#define BM 128
#define BN 128
#define BK 64

#define NBATCH 4
#define SEQ 2048
#define DIM 1024
#define MTOT (NBATCH * SEQ)   // 8192

__device__ __forceinline__ void async_ld16(const void* g, void* l) {
  __builtin_amdgcn_global_load_lds((__attribute__((address_space(1))) void*)(g),
                                   (__attribute__((address_space(3))) void*)(l),
                                   16, 0, 0);
}

// C[m0..+127][n0..+127] += A[m,k] * B[n,k]  (row-major, B^T GEMM)
// A,B f16; async global->LDS staging (XOR-swizzled slots); 4 waves 2x2;
// each wave 64x64 via 4x4 of 16x16x32 f16 MFMA.  (m97-style 2-barrier core,
// measured 910 TF on qkv — proven; do not phase-split, see r13 post-mortem.)
__device__ __forceinline__ void gemm_core(const _Float16* __restrict__ A, int lda,
                                          const _Float16* __restrict__ B, int ldb,
                                          int K, int m0, int n0,
                                          _Float16* As, _Float16* Bs,
                                          f32x4 (&acc)[4][4]) {
  const int t = threadIdx.x;
  const int w = t >> 6;
  const int lrow = t & 15;
  const int quad = (t >> 4) & 3;
  const int wm = (w >> 1) << 6;
  const int wn = (w & 1) << 6;

  // Staging: thread t covers tile row rb (+32 per i), global colblock
  // (t&7)^(rb&7) (XOR swizzle; LDS dest is the wave-contiguous slot t&7).
  const int rb = t >> 3;                               // 0..31
  const int co = (((t & 7) ^ (rb & 7)) << 3);          // swizzled source col
  const _Float16* Ap = A + (size_t)(m0 + rb) * lda + co;
  const _Float16* Bp = B + (size_t)(n0 + rb) * ldb + co;

  const int sw = lrow & 7;  // row-phase for read-side swizzle

  for (int k0 = 0; k0 < K; k0 += BK) {
#pragma unroll
    for (int i = 0; i < 4; ++i)
      async_ld16(Ap + (size_t)(i * 32) * lda + k0, As + i * 2048 + (w << 9));
#pragma unroll
    for (int i = 0; i < 4; ++i)
      async_ld16(Bp + (size_t)(i * 32) * ldb + k0, Bs + i * 2048 + (w << 9));
    __syncthreads();
#pragma unroll
    for (int kk = 0; kk < BK; kk += 32) {
      const int slot = ((kk >> 3) + quad) ^ sw;  // swizzled 8-elt slot index
      f16x8 af[4], bfr[4];
#pragma unroll
      for (int mi = 0; mi < 4; ++mi)
        af[mi] = *(const f16x8*)(As + (wm + mi * 16 + lrow) * BK + (slot << 3));
#pragma unroll
      for (int ni = 0; ni < 4; ++ni)
        bfr[ni] = *(const f16x8*)(Bs + (wn + ni * 16 + lrow) * BK + (slot << 3));
#pragma unroll
      for (int mi = 0; mi < 4; ++mi)
#pragma unroll
        for (int ni = 0; ni < 4; ++ni)
          acc[mi][ni] = __builtin_amdgcn_mfma_f32_16x16x32_f16(af[mi], bfr[ni],
                                                              acc[mi][ni], 0, 0, 0);
    }
    __syncthreads();
  }
}

// ---------------------------------------------------------------------------
// Kernel 0: fused f32 -> f16 cast for x, Wq, Wk, Wv.
__global__ __launch_bounds__(256) void split_all_kernel(
    const float* __restrict__ x, const float* __restrict__ Wq,
    const float* __restrict__ Wk, const float* __restrict__ Wv,
    _Float16* __restrict__ xh, _Float16* __restrict__ Wqh,
    _Float16* __restrict__ Wkh, _Float16* __restrict__ Wvh) {
  int r = blockIdx.x;
  const float* src;
  _Float16* dst;
  if (r < MTOT)            { src = x;  dst = xh;  }
  else if (r < MTOT + DIM) { src = Wq; dst = Wqh; r -= MTOT; }
  else if (r < MTOT + 2 * DIM) { src = Wk; dst = Wkh; r -= MTOT + DIM; }
  else                     { src = Wv; dst = Wvh; r -= MTOT + 2 * DIM; }
  const int t = threadIdx.x;
  const float4 v = ((const float4*)(src + (size_t)r * DIM))[t];
  f16x4 hi = {(_Float16)v.x, (_Float16)v.y, (_Float16)v.z, (_Float16)v.w};
  ((f16x4*)(dst + (size_t)r * DIM))[t] = hi;
}

// ---------------------------------------------------------------------------
// Kernel 1: QKV projections, all K=1024 (xh @ Wh^T). 1-D grid, 512 blocks/z.
// Decode: z = l>>9; within z: m = (l&7) + 8*(l>>6), n = (l>>3)&7  (8x8
// super-tiles; XCD = l&7 handles one m-row, B-tiles L2-resident).
__global__ __launch_bounds__(256, 2) void qkv_kernel(
    const _Float16* __restrict__ xh,
    const _Float16* __restrict__ Wqh, const float* __restrict__ bq,
    const _Float16* __restrict__ Wkh, const float* __restrict__ bk,
    const _Float16* __restrict__ Wvh, const float* __restrict__ bv,
    _Float16* __restrict__ Qp, _Float16* __restrict__ Kp,
    _Float16* __restrict__ Vt) {
  __shared__ alignas(16) _Float16 As[BM * BK];
  __shared__ alignas(16) _Float16 Bs[BN * BK];
  f32x4 acc[4][4] = {};
  const int l = blockIdx.x;
  const int z = l >> 9;
  const int r9 = l & 511;
  const int m0 = (((r9 & 7) | ((r9 >> 6) << 3))) * BM;
  const int n0 = ((r9 >> 3) & 7) * BN;
  const _Float16* W = (z == 0) ? Wqh : (z == 1) ? Wkh : Wvh;
  const float* bias = (z == 0) ? bq : (z == 1) ? bk : bv;
  gemm_core(xh, DIM, W, DIM, DIM, m0, n0, As, Bs, acc);

  const int t = threadIdx.x, w = t >> 6, lrow = t & 15, quad = (t >> 4) & 3;
  const int wm = (w >> 1) << 6, wn = (w & 1) << 6;
  if (z == 2) {
    // Vt[b][col][s]: 4 consecutive s per (mi,ni) -> vectorized f16x4 store.
    const int b = m0 >> 11;
    const int s_base = (m0 & (SEQ - 1)) + wm + quad * 4;
#pragma unroll
    for (int ni = 0; ni < 4; ++ni) {
      const int col = n0 + wn + ni * 16 + lrow;
      const float bb = bias[col];
      _Float16* vrow = Vt + (size_t)((b << 10) + col) * SEQ;
#pragma unroll
      for (int mi = 0; mi < 4; ++mi) {
        f16x4 v4 = {(_Float16)(acc[mi][ni][0] + bb),
                    (_Float16)(acc[mi][ni][1] + bb),
                    (_Float16)(acc[mi][ni][2] + bb),
                    (_Float16)(acc[mi][ni][3] + bb)};
        *(f16x4*)(vrow + s_base + mi * 16) = v4;
      }
    }
  } else {
    _Float16* base = (z == 0) ? Qp : Kp;
#pragma unroll
    for (int ni = 0; ni < 4; ++ni) {
      const int col = n0 + wn + ni * 16 + lrow;
      const float bb = bias[col];
#pragma unroll
      for (int mi = 0; mi < 4; ++mi) {
#pragma unroll
        for (int r = 0; r < 4; ++r) {
          const int row = m0 + wm + mi * 16 + quad * 4 + r;
          base[(size_t)row * DIM + col] = (_Float16)(acc[mi][ni][r] + bb);
        }
      }
    }
  }
}

// ---------------------------------------------------------------------------
// Kernel 2: scores[b] = Q[b] @ K[b]^T (K=1024), F16 out (round-16 delta).
// 1-D grid, 256 blocks/batch: s=r>>6 picks (m_sup=s&1, n_sup=s>>1);
// m=(r&7)+8*m_sup, n=((r>>3)&7)+8*n_sup.
__global__ __launch_bounds__(256, 2) void scores_kernel(
    const _Float16* __restrict__ Qp, const _Float16* __restrict__ Kp,
    _Float16* __restrict__ Sc) {
  __shared__ alignas(16) _Float16 As[BM * BK];
  __shared__ alignas(16) _Float16 Bs[BN * BK];
  f32x4 acc[4][4] = {};
  const int l = blockIdx.x;
  const int b = l >> 8;
  const int r8 = l & 255;
  const int s = r8 >> 6;
  const int m0 = ((r8 & 7) | ((s & 1) << 3)) * BM;
  const int n0 = (((r8 >> 3) & 7) | ((s >> 1) << 3)) * BN;
  gemm_core(Qp + (size_t)b * SEQ * DIM, DIM,
            Kp + (size_t)b * SEQ * DIM, DIM, DIM, m0, n0, As, Bs, acc);
  _Float16* out = Sc + (size_t)b * SEQ * SEQ;
  const int t = threadIdx.x, w = t >> 6, lrow = t & 15, quad = (t >> 4) & 3;
  const int wm = (w >> 1) << 6, wn = (w & 1) << 6;
#pragma unroll
  for (int ni = 0; ni < 4; ++ni) {
    const int col = n0 + wn + ni * 16 + lrow;
#pragma unroll
    for (int mi = 0; mi < 4; ++mi) {
#pragma unroll
      for (int r = 0; r < 4; ++r) {
        const int row = m0 + wm + mi * 16 + quad * 4 + r;
        out[(size_t)row * SEQ + col] = (_Float16)acc[mi][ni][r];
      }
    }
  }
}

// ---------------------------------------------------------------------------
// Kernel 3: row softmax, 2 rows per block (ILP), P = softmax(S)*(1/32), f16.
// Round-16: reads f16 Sc (one f16x8 per thread per row), math in f32.
__global__ __launch_bounds__(256) void softmax_kernel(const _Float16* __restrict__ Sc,
                                                      _Float16* __restrict__ P) {
  const int r0 = blockIdx.x * 2;  // rows r0, r0+1
  const _Float16* rowA = Sc + (size_t)r0 * SEQ;
  const _Float16* rowB = rowA + SEQ;
  _Float16* prowA = P + (size_t)r0 * SEQ;
  _Float16* prowB = prowA + SEQ;
  const int t = threadIdx.x;
  const int w = t >> 6;

  const f16x8 ha = ((const f16x8*)rowA)[t];   // cols t*8 .. t*8+7
  const f16x8 hb = ((const f16x8*)rowB)[t];
  float a[8], bb[8];
#pragma unroll
  for (int j = 0; j < 8; ++j) { a[j] = (float)ha[j]; bb[j] = (float)hb[j]; }

  float mA = fmaxf(fmaxf(fmaxf(a[0], a[1]), fmaxf(a[2], a[3])),
                   fmaxf(fmaxf(a[4], a[5]), fmaxf(a[6], a[7])));
  float mB = fmaxf(fmaxf(fmaxf(bb[0], bb[1]), fmaxf(bb[2], bb[3])),
                   fmaxf(fmaxf(bb[4], bb[5]), fmaxf(bb[6], bb[7])));
#pragma unroll
  for (int o = 32; o; o >>= 1) {
    mA = fmaxf(mA, __shfl_down(mA, o));
    mB = fmaxf(mB, __shfl_down(mB, o));
  }
  __shared__ float red[16];
  if ((t & 63) == 0) { red[w] = mA; red[w + 4] = mB; }
  __syncthreads();
  mA = fmaxf(fmaxf(red[0], red[1]), fmaxf(red[2], red[3]));
  mB = fmaxf(fmaxf(red[4], red[5]), fmaxf(red[6], red[7]));

  float eA[8], eB[8];
#pragma unroll
  for (int j = 0; j < 8; ++j) {
    eA[j] = __expf(a[j] - mA);
    eB[j] = __expf(bb[j] - mB);
  }
  float sA = ((eA[0] + eA[1]) + (eA[2] + eA[3])) + ((eA[4] + eA[5]) + (eA[6] + eA[7]));
  float sB = ((eB[0] + eB[1]) + (eB[2] + eB[3])) + ((eB[4] + eB[5]) + (eB[6] + eB[7]));
#pragma unroll
  for (int o = 32; o; o >>= 1) {
    sA += __shfl_down(sA, o);
    sB += __shfl_down(sB, o);
  }
  if ((t & 63) == 0) { red[8 + w] = sA; red[12 + w] = sB; }
  __syncthreads();
  sA = (red[8] + red[9]) + (red[10] + red[11]);
  sB = (red[12] + red[13]) + (red[14] + red[15]);

  const float scA = 0.03125f / sA;  // post-softmax 1/sqrt(Dk)=1/32 folded in
  const float scB = 0.03125f / sB;
  f16x8 oA, oB;
#pragma unroll
  for (int j = 0; j < 8; ++j) {
    oA[j] = (_Float16)(eA[j] * scA);
    oB[j] = (_Float16)(eB[j] * scB);
  }
  ((f16x8*)prowA)[t] = oA;
  ((f16x8*)prowB)[t] = oB;
}

// ---------------------------------------------------------------------------
// Kernel 4: O[b] = P[b] @ V[b]  (Vt [v][s] -> B^T GEMM, K=2048), f32 out.
// 1-D grid, 128 blocks/batch: m=(r&7)+8*(r>>6), n=(r>>3)&7.
__global__ __launch_bounds__(256, 2) void pv_kernel(
    const _Float16* __restrict__ P, const _Float16* __restrict__ Vt,
    float* __restrict__ out) {
  __shared__ alignas(16) _Float16 As[BM * BK];
  __shared__ alignas(16) _Float16 Bs[BN * BK];
  f32x4 acc[4][4] = {};
  const int l = blockIdx.x;
  const int b = l >> 7;
  const int r7 = l & 127;
  const int m0 = ((r7 & 7) | ((r7 >> 6) << 3)) * BM;
  const int n0 = ((r7 >> 3) & 7) * BN;
  gemm_core(P + (size_t)b * SEQ * SEQ, SEQ,
            Vt + (size_t)b * DIM * SEQ, SEQ, SEQ, m0, n0, As, Bs, acc);
  float* ob = out + (size_t)b * SEQ * DIM;
  const int t = threadIdx.x, w = t >> 6, lrow = t & 15, quad = (t >> 4) & 3;
  const int wm = (w >> 1) << 6, wn = (w & 1) << 6;
#pragma unroll
  for (int ni = 0; ni < 4; ++ni) {
    const int col = n0 + wn + ni * 16 + lrow;
#pragma unroll
    for (int mi = 0; mi < 4; ++mi) {
#pragma unroll
      for (int r = 0; r < 4; ++r) {
        const int row = m0 + wm + mi * 16 + quad * 4 + r;
        ob[(size_t)row * DIM + col] = acc[mi][ni][r];
      }
    }
  }
}

// ---------------------------------------------------------------------------
extern "C" void kernel_launch(void* const* d_in, const int* in_sizes, int n_in,
                              void* d_out, int out_size, void* d_ws, size_t ws_size,
                              hipStream_t stream) {
  const float* x  = (const float*)d_in[0];
  const float* Wq = (const float*)d_in[1];
  const float* bq = (const float*)d_in[2];
  const float* Wk = (const float*)d_in[3];
  const float* bk = (const float*)d_in[4];
  const float* Wv = (const float*)d_in[5];
  const float* bv = (const float*)d_in[6];
  float* out = (float*)d_out;  // reference output dtype is float32

  char* ws = (char*)d_ws;
  _Float16* Qp  = (_Float16*)(ws);                 // 16 MB [8192][1024]
  _Float16* Kp  = (_Float16*)(ws + 16777216);      // 16 MB
  _Float16* Vt  = (_Float16*)(ws + 33554432);      // 16 MB [4][1024][2048]
  _Float16* Sc  = (_Float16*)(ws + 50331648);      // 32 MB [4][2048][2048] f16
  _Float16* P   = (_Float16*)(ws + 117440512);     // 32 MB [4][2048][2048] f16
  // xh + W hi planes alias the Sc region (dead once scores_kernel runs).
  _Float16* xh  = (_Float16*)(ws + 50331648);      // 16 MB [8192][1024]
  _Float16* Wqh = (_Float16*)(ws + 67108864);      //  2 MB (dead after qkv)
  _Float16* Wkh = (_Float16*)(ws + 69206016);      //  2 MB (dead after qkv)
  _Float16* Wvh = (_Float16*)(ws + 71303168);      //  2 MB (dead after qkv)
  // peak 150,994,944 B

  dim3 blk(256, 1, 1);
  split_all_kernel<<<dim3(MTOT + 3 * DIM), blk, 0, stream>>>(
      x, Wq, Wk, Wv, xh, Wqh, Wkh, Wvh);
  qkv_kernel<<<dim3(3 * 512), blk, 0, stream>>>(
      xh, Wqh, bq, Wkh, bk, Wvh, bv, Qp, Kp, Vt);
  scores_kernel<<<dim3(NBATCH * 256), blk, 0, stream>>>(Qp, Kp, Sc);
  softmax_kernel<<<dim3(MTOT / 2), blk, 0, stream>>>(Sc, P);
  pv_kernel<<<dim3(NBATCH * 128), blk, 0, stream>>>(P, Vt, out);
}